// Round 8
// baseline (980.544 us; speedup 1.0000x reference)
//
#include <hip/hip_runtime.h>
#include <hip/hip_bf16.h>
#include <cstdint>
#include <cstddef>

// ---------- types ----------
typedef __attribute__((ext_vector_type(8))) short short8;   // bf16 x8 (4 VGPRs)
typedef __attribute__((ext_vector_type(4))) short short4v;  // bf16 x4
typedef __attribute__((ext_vector_type(4))) float floatx4;

#define D_MODEL 512
#define HDIM    2048
#define TSEQ    16384
#define NTOK    65536   // B*T = 4*16384

// ---------- helpers ----------
__device__ __forceinline__ float bf2f(short s) {
  union { unsigned u; float f; } v; v.u = ((unsigned)(unsigned short)s) << 16; return v.f;
}
__device__ __forceinline__ short f2bf(float f) {
  union { float fv; unsigned u; } v; v.fv = f;
  unsigned u = v.u;
  u += 0x7FFFu + ((u >> 16) & 1u);   // RNE
  return (short)(u >> 16);
}
__device__ __forceinline__ void gload_lds16(const void* g, void* l) {
  // width=16 async global->LDS; LDS dest = wave-uniform base + lane*16 (m104)
  __builtin_amdgcn_global_load_lds((const __attribute__((address_space(1))) void*)g,
                                   (__attribute__((address_space(3))) void*)l, 16, 0, 0);
}

// ---------- weight convert + transpose: W[K][N] f32 -> Wt[N][K] bf16 ----------
__global__ void wt_transpose(const float* __restrict__ W, short* __restrict__ Wt,
                             const int K, const int N) {
  __shared__ float t[64][65];
  const int tid = threadIdx.x;
  const long k0 = (long)blockIdx.x * 64;
  const long n0 = (long)blockIdx.y * 64;
  const int rr = tid >> 4;
  const int cc = (tid & 15) * 4;
#pragma unroll
  for (int i = 0; i < 4; ++i) {
    const int r = rr + i * 16;
    const float4 v = *(const float4*)(W + (k0 + r) * N + n0 + cc);
    t[r][cc + 0] = v.x; t[r][cc + 1] = v.y; t[r][cc + 2] = v.z; t[r][cc + 3] = v.w;
  }
  __syncthreads();
#pragma unroll
  for (int i = 0; i < 4; ++i) {
    const int n = rr + i * 16;
    short4v o;
    o[0] = f2bf(t[cc + 0][n]);
    o[1] = f2bf(t[cc + 1][n]);
    o[2] = f2bf(t[cc + 2][n]);
    o[3] = f2bf(t[cc + 3][n]);
    *(short4v*)(Wt + (n0 + n) * K + k0 + cc) = o;
  }
}

// conv_w [512][17] f32 -> wT [17][512] f32
__global__ void convw_transpose(const float* __restrict__ cw, float* __restrict__ wT) {
  const int idx = blockIdx.x * 256 + threadIdx.x;
  if (idx >= 17 * D_MODEL) return;
  const int k = idx / D_MODEL;
  const int c = idx % D_MODEL;
  wT[idx] = cw[c * 17 + k];
}

// ---------- RMSNorm: one wave per row, f32 in -> bf16 out ----------
__global__ void rmsnorm_kernel(const float* __restrict__ x, const float* __restrict__ w,
                               short* __restrict__ outp) {
  const int lane = threadIdx.x & 63;
  const long row = (long)blockIdx.x * 4 + (threadIdx.x >> 6);
  const float* xr = x + row * D_MODEL + lane * 8;
  const float4 a = *(const float4*)xr;
  const float4 b = *(const float4*)(xr + 4);
  float ss = a.x * a.x + a.y * a.y + a.z * a.z + a.w * a.w
           + b.x * b.x + b.y * b.y + b.z * b.z + b.w * b.w;
#pragma unroll
  for (int m = 32; m; m >>= 1) ss += __shfl_xor(ss, m);
  const float scale = rsqrtf(ss * (1.0f / D_MODEL) + 1e-6f);
  const float4 wa = *(const float4*)(w + lane * 8);
  const float4 wb = *(const float4*)(w + lane * 8 + 4);
  short8 o;
  o[0] = f2bf(a.x * scale * wa.x);
  o[1] = f2bf(a.y * scale * wa.y);
  o[2] = f2bf(a.z * scale * wa.z);
  o[3] = f2bf(a.w * scale * wa.w);
  o[4] = f2bf(b.x * scale * wb.x);
  o[5] = f2bf(b.y * scale * wb.y);
  o[6] = f2bf(b.z * scale * wb.z);
  o[7] = f2bf(b.w * scale * wb.w);
  *(short8*)(outp + row * D_MODEL + lane * 8) = o;
}

// ---------- causal depthwise conv (K=17, dilation=1), bf16 in/out ----------
__global__ void dwconv_kernel(const short* __restrict__ hn, const float* __restrict__ wT,
                              short* __restrict__ hc) {
  const int tid = threadIdx.x;
  const int chunk = tid & 63;                       // 64 chunks of 8 channels
  const long row = (long)blockIdx.x * 4 + (tid >> 6);
  const int t = (int)(row & (TSEQ - 1));
  const int c0 = chunk * 8;
  float acc[8];
#pragma unroll
  for (int j = 0; j < 8; ++j) acc[j] = 0.f;
  const int kmin = (t >= 16) ? 0 : (16 - t);
  for (int k = kmin; k < 17; ++k) {
    const short8 h = *(const short8*)(hn + (row - 16 + k) * D_MODEL + c0);
    const float* wp = wT + k * D_MODEL + c0;
    const float4 w0 = *(const float4*)(wp);
    const float4 w1 = *(const float4*)(wp + 4);
    acc[0] += bf2f(h[0]) * w0.x;
    acc[1] += bf2f(h[1]) * w0.y;
    acc[2] += bf2f(h[2]) * w0.z;
    acc[3] += bf2f(h[3]) * w0.w;
    acc[4] += bf2f(h[4]) * w1.x;
    acc[5] += bf2f(h[5]) * w1.y;
    acc[6] += bf2f(h[6]) * w1.z;
    acc[7] += bf2f(h[7]) * w1.w;
  }
  short8 o;
#pragma unroll
  for (int j = 0; j < 8; ++j) o[j] = f2bf(acc[j]);
  *(short8*)(hc + row * D_MODEL + c0) = o;
}

// ---------- 128x128 GEMM, A via LDS (dbuf), B direct global->reg ----------
// C[M][N] = A[M][K](bf16) x Bt[N][K](bf16). 256 threads = 4 waves (2M x 2N),
// wave tile 64x64. BK=64. LDS = 2 x (128x64) x 2B = 32 KiB (A only).
// B (the weight, 0.5-2 MB) is L2/L1-resident: fragments loaded straight
// global->reg as short8 (4 lanes x 16B cover one 64B line -> fully efficient).
// This halves LDS read AND DMA-write traffic vs B-in-LDS, and the small LDS +
// ~155 VGPR (launch_bounds(256,3)) give 3 blocks/CU = 12 waves/CU: independent
// blocks cover each other's barrier/latency stalls (m114 wave-level overlap).
// A staged with global_load_lds (linear dest) + both-sides XOR chunk swizzle
// (pre-swizzled global source, swizzled ds_read) -> 0 bank conflicts (R1-R6).
// EPI 0: u = sigmoid(acc) * hc   (aux=hc bf16, outp=u bf16; in-place OK)
// EPI 1: out = x + acc           (aux=x f32,  outp=f32)
// EPI 2: out = gelu_tanh(acc)    (outp=bf16)
// EPI 3: out += acc              (outp=f32, read-modify-write)
template <int EPI>
__global__ __launch_bounds__(256, 3)
void gemm128(const short* __restrict__ A, const short* __restrict__ Bt,
             const int K, const int N, const int nbn,
             const void* __restrict__ aux, void* __restrict__ outp) {
  __shared__ short Alds[2 * 128 * 64];   // [buf][row 128][k 64]
  const int tid = threadIdx.x;
  const int lane = tid & 63;
  const int w = tid >> 6;
  const int wm = w >> 1;          // 0..1  (M half of block)
  const int wn = w & 1;           // 0..1  (N half of block)

  // XCD-chunked swizzle (all call sites have gridDim.x % 8 == 0);
  // consecutive wids share the A-panel (nbn fastest) -> A L2-resident per XCD.
  const int nwg = gridDim.x;
  const int cpx = nwg >> 3;
  const int bid = blockIdx.x;
  const int wid = (bid & 7) * cpx + (bid >> 3);
  const int brow = (wid / nbn) * 128;
  const int bcol = (wid % nbn) * 128;

  floatx4 acc[4][4];
#pragma unroll
  for (int i = 0; i < 4; ++i)
#pragma unroll
    for (int j = 0; j < 4; ++j) acc[i][j] = {0.f, 0.f, 0.f, 0.f};

  short8 af[4][2];   // A frags: 4 m-frags x 2 k-slices
  short8 bfr[4][2];  // B frags: 4 n-frags x 2 k-slices

  // A staging: per wave 4 instrs, rows w*32 + j*8 + (lane>>3), 16B chunks;
  // source chunk pre-swizzled so linear LDS dest + XOR read are conflict-free.
  const int chunkx = (lane & 7) ^ (lane >> 3);
  const short* gA = A + ((long)(brow + w * 32 + (lane >> 3))) * K + chunkx * 8;
  // B fragment source: lane holds col = base + (lane&15), k = ks*32 + (lane>>4)*8 ..+8
  const int kchunk = lane >> 4;   // 0..3
  const short* gB = Bt + ((long)(bcol + wn * 64 + (lane & 15))) * K + kchunk * 8;

#define STGA(BUF, koff)                                                        \
  { _Pragma("unroll")                                                          \
    for (int j = 0; j < 4; ++j)                                                \
      gload_lds16(gA + (long)j * 8 * K + (koff),                               \
                  &Alds[((BUF) * 128 + w * 32 + j * 8) * 64]); }

  const int nkt = K >> 6;
  // prologue
  STGA(0, 0);
  __syncthreads();

  int buf = 0;
  for (int kt = 0; kt < nkt; ++kt) {
    if (kt + 1 < nkt) STGA(buf ^ 1, (kt + 1) * 64);

    // B frags: global->reg (L2-resident weight)
#pragma unroll
    for (int ni = 0; ni < 4; ++ni)
#pragma unroll
      for (int ks = 0; ks < 2; ++ks)
        bfr[ni][ks] = *(const short8*)(gB + (long)ni * 16 * K + kt * 64 + ks * 32);

    // A frags: LDS (swizzled read)
#pragma unroll
    for (int mi = 0; mi < 4; ++mi) {
      const int r = wm * 64 + mi * 16 + (lane & 15);
#pragma unroll
      for (int ks = 0; ks < 2; ++ks) {
        const int c = (ks * 4 + kchunk) ^ (r & 7);
        af[mi][ks] = *(const short8*)(&Alds[(buf * 128 + r) * 64 + c * 8]);
      }
    }

#pragma unroll
    for (int mi = 0; mi < 4; ++mi)
#pragma unroll
      for (int ni = 0; ni < 4; ++ni)
#pragma unroll
        for (int ks = 0; ks < 2; ++ks)
          acc[mi][ni] = __builtin_amdgcn_mfma_f32_16x16x32_bf16(
              af[mi][ks], bfr[ni][ks], acc[mi][ni], 0, 0, 0);

    __syncthreads();
    buf ^= 1;
  }
#undef STGA

  // epilogue: C/D layout col=lane&15, row=(lane>>4)*4+j. 32-bit index math.
#pragma unroll
  for (int mi = 0; mi < 4; ++mi) {
    const int r0 = brow + wm * 64 + mi * 16 + (lane >> 4) * 4;
#pragma unroll
    for (int j = 0; j < 4; ++j) {
      const int rb = (r0 + j) * N;
      const int gcb = bcol + wn * 64 + (lane & 15);
#pragma unroll
      for (int ni = 0; ni < 4; ++ni) {
        const int idx = rb + gcb + ni * 16;
        const float v = acc[mi][ni][j];
        if (EPI == 0) {
          const float hcv = bf2f(((const short*)aux)[idx]);
          const float g = 1.f / (1.f + __expf(-v));
          ((short*)outp)[idx] = f2bf(g * hcv);
        } else if (EPI == 1) {
          ((float*)outp)[idx] = ((const float*)aux)[idx] + v;
        } else if (EPI == 2) {
          const float x3 = v * v * v;
          const float z = 0.7978845608028654f * (v + 0.044715f * x3);
          const float th = 1.f - 2.f / (__expf(2.f * z) + 1.f);   // tanh(z)
          ((short*)outp)[idx] = f2bf(0.5f * v * (1.f + th));
        } else {
          ((float*)outp)[idx] += v;
        }
      }
    }
  }
}

// ---------- launch ----------
extern "C" void kernel_launch(void* const* d_in, const int* in_sizes, int n_in,
                              void* d_out, int out_size, void* d_ws, size_t ws_size,
                              hipStream_t stream) {
  const float* x      = (const float*)d_in[0];
  const float* ln1_w  = (const float*)d_in[1];
  const float* gate_w = (const float*)d_in[2];   // [512][512]
  const float* conv_w = (const float*)d_in[3];   // [512][17]
  const float* proj_w = (const float*)d_in[4];   // [512][512]
  const float* ln2_w  = (const float*)d_in[5];
  const float* mlp_w1 = (const float*)d_in[6];   // [512][2048]
  const float* mlp_w2 = (const float*)d_in[7];   // [2048][512]
  float* out = (float*)d_out;
  char* ws = (char*)d_ws;

  // workspace layout (bytes), all offsets 256B-aligned
  short* hn      = (short*)(ws + 0);                       // 64 MiB  (also hn2 later)
  short* hc      = (short*)(ws + 67108864L);               // 64 MiB  (hc, then u in-place)
  short* mid     = (short*)(ws + 134217728L);              // 256 MiB
  short* gate_wt = (short*)(ws + 402653184L);              // 512 KiB [512][512]
  short* proj_wt = (short*)(ws + 403177472L);              // 512 KiB
  short* w1t     = (short*)(ws + 403701760L);              // 2 MiB   [2048][512]
  short* w2t     = (short*)(ws + 405798912L);              // 2 MiB   [512][2048]
  float* convwT  = (float*)(ws + 407896064L);              // 34 KiB  [17][512]

  const dim3 b256(256);

  // weights -> bf16 transposed (per-call; deterministic, ~5 MB)
  wt_transpose<<<dim3(8, 8),  b256, 0, stream>>>(gate_w, gate_wt, 512, 512);
  wt_transpose<<<dim3(8, 8),  b256, 0, stream>>>(proj_w, proj_wt, 512, 512);
  wt_transpose<<<dim3(8, 32), b256, 0, stream>>>(mlp_w1, w1t, 512, 2048);
  wt_transpose<<<dim3(32, 8), b256, 0, stream>>>(mlp_w2, w2t, 2048, 512);
  convw_transpose<<<34, b256, 0, stream>>>(conv_w, convwT);

  // 1) hn = rmsnorm(x, ln1_w)
  rmsnorm_kernel<<<NTOK / 4, b256, 0, stream>>>(x, ln1_w, hn);
  // 2) hc = causal_dwconv(hn)
  dwconv_kernel<<<NTOK / 4, b256, 0, stream>>>(hn, convwT, hc);
  // 3) u = sigmoid(hn @ gate_w) * hc   (in-place into hc)
  gemm128<0><<<512 * 4, b256, 0, stream>>>(hn, gate_wt, 512, 512, 4, hc, hc);
  // 4) x2 = x + u @ proj_w  -> d_out (f32)
  gemm128<1><<<512 * 4, b256, 0, stream>>>(hc, proj_wt, 512, 512, 4, x, out);
  // 5) hn2 = rmsnorm(x2, ln2_w)  (reuse hn buffer)
  rmsnorm_kernel<<<NTOK / 4, b256, 0, stream>>>(out, ln2_w, hn);
  // 6) mid = gelu(hn2 @ mlp_w1)
  gemm128<2><<<512 * 16, b256, 0, stream>>>(hn, w1t, 512, 2048, 16, nullptr, mid);
  // 7) out += mid @ mlp_w2
  gemm128<3><<<512 * 4, b256, 0, stream>>>(mid, w2t, 2048, 512, 4, nullptr, out);
}

// Round 9
// 721.196 us; speedup vs baseline: 1.3596x; 1.3596x over previous
//
#include <hip/hip_runtime.h>
#include <hip/hip_bf16.h>
#include <cstdint>
#include <cstddef>

// ---------- types ----------
typedef __attribute__((ext_vector_type(8))) short short8;   // bf16 x8 (4 VGPRs)
typedef __attribute__((ext_vector_type(4))) short short4v;  // bf16 x4
typedef __attribute__((ext_vector_type(4))) float floatx4;

#define D_MODEL 512
#define HDIM    2048
#define TSEQ    16384
#define NTOK    65536   // B*T = 4*16384

// ---------- helpers ----------
__device__ __forceinline__ float bf2f(short s) {
  union { unsigned u; float f; } v; v.u = ((unsigned)(unsigned short)s) << 16; return v.f;
}
__device__ __forceinline__ short f2bf(float f) {
  union { float fv; unsigned u; } v; v.fv = f;
  unsigned u = v.u;
  u += 0x7FFFu + ((u >> 16) & 1u);   // RNE
  return (short)(u >> 16);
}
__device__ __forceinline__ void gload_lds16(const void* g, void* l) {
  // width=16 async global->LDS; LDS dest = wave-uniform base + lane*16 (m104)
  __builtin_amdgcn_global_load_lds((const __attribute__((address_space(1))) void*)g,
                                   (__attribute__((address_space(3))) void*)l, 16, 0, 0);
}

// ---------- weight convert + transpose: W[K][N] f32 -> Wt[N][K] bf16 ----------
__global__ void wt_transpose(const float* __restrict__ W, short* __restrict__ Wt,
                             const int K, const int N) {
  __shared__ float t[64][65];
  const int tid = threadIdx.x;
  const long k0 = (long)blockIdx.x * 64;
  const long n0 = (long)blockIdx.y * 64;
  const int rr = tid >> 4;
  const int cc = (tid & 15) * 4;
#pragma unroll
  for (int i = 0; i < 4; ++i) {
    const int r = rr + i * 16;
    const float4 v = *(const float4*)(W + (k0 + r) * N + n0 + cc);
    t[r][cc + 0] = v.x; t[r][cc + 1] = v.y; t[r][cc + 2] = v.z; t[r][cc + 3] = v.w;
  }
  __syncthreads();
#pragma unroll
  for (int i = 0; i < 4; ++i) {
    const int n = rr + i * 16;
    short4v o;
    o[0] = f2bf(t[cc + 0][n]);
    o[1] = f2bf(t[cc + 1][n]);
    o[2] = f2bf(t[cc + 2][n]);
    o[3] = f2bf(t[cc + 3][n]);
    *(short4v*)(Wt + (n0 + n) * K + k0 + cc) = o;
  }
}

// conv_w [512][17] f32 -> wT [17][512] f32
__global__ void convw_transpose(const float* __restrict__ cw, float* __restrict__ wT) {
  const int idx = blockIdx.x * 256 + threadIdx.x;
  if (idx >= 17 * D_MODEL) return;
  const int k = idx / D_MODEL;
  const int c = idx % D_MODEL;
  wT[idx] = cw[c * 17 + k];
}

// ---------- RMSNorm: one wave per row, f32 in -> bf16 out ----------
__global__ void rmsnorm_kernel(const float* __restrict__ x, const float* __restrict__ w,
                               short* __restrict__ outp) {
  const int lane = threadIdx.x & 63;
  const long row = (long)blockIdx.x * 4 + (threadIdx.x >> 6);
  const float* xr = x + row * D_MODEL + lane * 8;
  const float4 a = *(const float4*)xr;
  const float4 b = *(const float4*)(xr + 4);
  float ss = a.x * a.x + a.y * a.y + a.z * a.z + a.w * a.w
           + b.x * b.x + b.y * b.y + b.z * b.z + b.w * b.w;
#pragma unroll
  for (int m = 32; m; m >>= 1) ss += __shfl_xor(ss, m);
  const float scale = rsqrtf(ss * (1.0f / D_MODEL) + 1e-6f);
  const float4 wa = *(const float4*)(w + lane * 8);
  const float4 wb = *(const float4*)(w + lane * 8 + 4);
  short8 o;
  o[0] = f2bf(a.x * scale * wa.x);
  o[1] = f2bf(a.y * scale * wa.y);
  o[2] = f2bf(a.z * scale * wa.z);
  o[3] = f2bf(a.w * scale * wa.w);
  o[4] = f2bf(b.x * scale * wb.x);
  o[5] = f2bf(b.y * scale * wb.y);
  o[6] = f2bf(b.z * scale * wb.z);
  o[7] = f2bf(b.w * scale * wb.w);
  *(short8*)(outp + row * D_MODEL + lane * 8) = o;
}

// ---------- causal depthwise conv (K=17, dilation=1), bf16 in/out ----------
__global__ void dwconv_kernel(const short* __restrict__ hn, const float* __restrict__ wT,
                              short* __restrict__ hc) {
  const int tid = threadIdx.x;
  const int chunk = tid & 63;                       // 64 chunks of 8 channels
  const long row = (long)blockIdx.x * 4 + (tid >> 6);
  const int t = (int)(row & (TSEQ - 1));
  const int c0 = chunk * 8;
  float acc[8];
#pragma unroll
  for (int j = 0; j < 8; ++j) acc[j] = 0.f;
  const int kmin = (t >= 16) ? 0 : (16 - t);
  for (int k = kmin; k < 17; ++k) {
    const short8 h = *(const short8*)(hn + (row - 16 + k) * D_MODEL + c0);
    const float* wp = wT + k * D_MODEL + c0;
    const float4 w0 = *(const float4*)(wp);
    const float4 w1 = *(const float4*)(wp + 4);
    acc[0] += bf2f(h[0]) * w0.x;
    acc[1] += bf2f(h[1]) * w0.y;
    acc[2] += bf2f(h[2]) * w0.z;
    acc[3] += bf2f(h[3]) * w0.w;
    acc[4] += bf2f(h[4]) * w1.x;
    acc[5] += bf2f(h[5]) * w1.y;
    acc[6] += bf2f(h[6]) * w1.z;
    acc[7] += bf2f(h[7]) * w1.w;
  }
  short8 o;
#pragma unroll
  for (int j = 0; j < 8; ++j) o[j] = f2bf(acc[j]);
  *(short8*)(hc + row * D_MODEL + c0) = o;
}

// ---------- 128x128 GEMM, dbuf LDS, counted vmcnt, 2 blocks/CU ----------
// C[M][N] = A[M][K](bf16) x Bt[N][K](bf16). 256 threads = 4 waves (2M x 2N),
// wave tile 64x64. BK=64. LDS = 2buf x (A 128x64 + B 128x64) x 2B = 64 KiB ->
// 2 independent blocks/CU (8 waves/CU): one block's barrier/wait stalls are
// covered by the other block's MFMAs (m114 inter-block overlap — the missing
// piece of the 1-block/CU 256^2 structure that plateaued at ~600 TF).
// Per K-tile (2 barriers, hazard-ledger-verified):
//   { stage(t+1)->buf^1 (8 DMA); vmcnt(8); BAR;        // all waves' stage(t) visible
//     16 asm ds_read(buf); lgkm0; 32 MFMA (setprio); BAR }  // reads drained before
//                                                      // next tile's stage hits buf
// Counted vmcnt(8) keeps 1 tile (8 loads) in flight across barriers (T4); only the
// tail drains to 0. Frag reads are inline-asm ds_read_b128 (defeats conservative
// vmcnt(0) LDS-DMA alias drains; rule #18 sched_barrier(0) after each waitcnt).
// Both-sides XOR chunk swizzle (pre-swizzled global src, swizzled read) -> 0 bank
// conflicts (verified R1-R6). XCD-chunked block swizzle (grid % 8 == 0).
#define PHASE_BAR() __builtin_amdgcn_s_barrier()
#define LGKM0() { asm volatile("s_waitcnt lgkmcnt(0)" ::: "memory"); __builtin_amdgcn_sched_barrier(0); }
#define VMC8()  { asm volatile("s_waitcnt vmcnt(8)"   ::: "memory"); __builtin_amdgcn_sched_barrier(0); }
#define VMC0()  { asm volatile("s_waitcnt vmcnt(0)"   ::: "memory"); __builtin_amdgcn_sched_barrier(0); }
#define DSR1(dst, addr, imm) \
  asm volatile("ds_read_b128 %0, %1 offset:%2" : "=v"(dst) : "v"(addr), "i"(imm))

template <int EPI>
__global__ __launch_bounds__(256, 2)
void gemm128(const short* __restrict__ A, const short* __restrict__ Bt,
             const int K, const int N, const int nbn,
             const void* __restrict__ aux, void* __restrict__ outp) {
  __shared__ short Alds[2 * 128 * 64];   // [buf][row 128][k 64]
  __shared__ short Blds[2 * 128 * 64];
  const int tid = threadIdx.x;
  const int lane = tid & 63;
  const int w = tid >> 6;         // 0..3
  const int wm = w >> 1;          // 0..1  (M half)
  const int wn = w & 1;           // 0..1  (N half)

  // XCD-chunked swizzle; consecutive wids share the A-panel (nbn fastest)
  const int nwg = gridDim.x;
  const int cpx = nwg >> 3;
  const int bid = blockIdx.x;
  const int wid = (bid & 7) * cpx + (bid >> 3);
  const int brow = (wid / nbn) * 128;
  const int bcol = (wid % nbn) * 128;

  floatx4 acc[4][4];
#pragma unroll
  for (int i = 0; i < 4; ++i)
#pragma unroll
    for (int j = 0; j < 4; ++j) acc[i][j] = {0.f, 0.f, 0.f, 0.f};

  short8 af[4][2];   // A frags: 4 m-frags x 2 k-slices
  short8 bfr[4][2];  // B frags: 4 n-frags x 2 k-slices

  // staging: wave w covers rows w*32..w*32+31, 8 rows per DMA (64 lanes x 16B);
  // source chunk pre-swizzled so linear LDS dest + XOR ds_read are conflict-free.
  const int chunkx = (lane & 7) ^ (lane >> 3);
  const short* gA = A + ((long)(brow + w * 32 + (lane >> 3))) * K + chunkx * 8;
  const short* gB = Bt + ((long)(bcol + w * 32 + (lane >> 3))) * K + chunkx * 8;
  const int kchunk = lane >> 4;   // 0..3

  // asm ds_read addresses: frag byte = BUF*16384 + r*128 + c*16,
  //   r = (wm|wn)*64 + frag*16 + (lane&15), c = (ks*4+kchunk)^(lane&7)
  const unsigned Abase = (unsigned)(uintptr_t)(__attribute__((address_space(3))) short*)Alds;
  const unsigned Bbase = (unsigned)(uintptr_t)(__attribute__((address_space(3))) short*)Blds;
  const unsigned lanelo = (unsigned)((lane & 15) * 128);
  const unsigned c0t = (unsigned)(((0 + kchunk) ^ (lane & 7)) * 16);
  const unsigned c1t = (unsigned)(((4 + kchunk) ^ (lane & 7)) * 16);
  const unsigned adrA0 = Abase + (unsigned)(wm * 8192) + lanelo + c0t;
  const unsigned adrA1 = Abase + (unsigned)(wm * 8192) + lanelo + c1t;
  const unsigned adrB0 = Bbase + (unsigned)(wn * 8192) + lanelo + c0t;
  const unsigned adrB1 = Bbase + (unsigned)(wn * 8192) + lanelo + c1t;

#define STG(BUF, koff)                                                         \
  { _Pragma("unroll")                                                          \
    for (int j = 0; j < 4; ++j)                                                \
      gload_lds16(gA + (long)j * 8 * K + (koff),                               \
                  &Alds[((BUF) * 128 + w * 32 + j * 8) * 64]);                 \
    _Pragma("unroll")                                                          \
    for (int j = 0; j < 4; ++j)                                                \
      gload_lds16(gB + (long)j * 8 * K + (koff),                               \
                  &Blds[((BUF) * 128 + w * 32 + j * 8) * 64]); }

#define READS(BUF) {                                                           \
    DSR1(af[0][0],  adrA0, (BUF)*16384 + 0*2048);                              \
    DSR1(af[0][1],  adrA1, (BUF)*16384 + 0*2048);                              \
    DSR1(af[1][0],  adrA0, (BUF)*16384 + 1*2048);                              \
    DSR1(af[1][1],  adrA1, (BUF)*16384 + 1*2048);                              \
    DSR1(af[2][0],  adrA0, (BUF)*16384 + 2*2048);                              \
    DSR1(af[2][1],  adrA1, (BUF)*16384 + 2*2048);                              \
    DSR1(af[3][0],  adrA0, (BUF)*16384 + 3*2048);                              \
    DSR1(af[3][1],  adrA1, (BUF)*16384 + 3*2048);                              \
    DSR1(bfr[0][0], adrB0, (BUF)*16384 + 0*2048);                              \
    DSR1(bfr[0][1], adrB1, (BUF)*16384 + 0*2048);                              \
    DSR1(bfr[1][0], adrB0, (BUF)*16384 + 1*2048);                              \
    DSR1(bfr[1][1], adrB1, (BUF)*16384 + 1*2048);                              \
    DSR1(bfr[2][0], adrB0, (BUF)*16384 + 2*2048);                              \
    DSR1(bfr[2][1], adrB1, (BUF)*16384 + 2*2048);                              \
    DSR1(bfr[3][0], adrB0, (BUF)*16384 + 3*2048);                              \
    DSR1(bfr[3][1], adrB1, (BUF)*16384 + 3*2048); }

#define MMACL_ALL()                                                            \
  { __builtin_amdgcn_s_setprio(1);                                             \
    _Pragma("unroll")                                                          \
    for (int mi = 0; mi < 4; ++mi)                                             \
      _Pragma("unroll")                                                        \
      for (int ni = 0; ni < 4; ++ni)                                           \
        _Pragma("unroll")                                                      \
        for (int ks = 0; ks < 2; ++ks)                                         \
          acc[mi][ni] = __builtin_amdgcn_mfma_f32_16x16x32_bf16(               \
              af[mi][ks], bfr[ni][ks], acc[mi][ni], 0, 0, 0);                  \
    __builtin_amdgcn_s_setprio(0); }

  // TILE: DOST stages tile t+1 into BUF^1; W8 counted wait (steady), W0 tail drain.
#define TILE(BUF, DOST, W8, W0, LASTT, koff)                                   \
  {                                                                            \
    if (DOST) STG((BUF) ^ 1, koff);                                            \
    if (W8) VMC8();                                                            \
    if (W0) VMC0();                                                            \
    PHASE_BAR();                                                               \
    READS(BUF); LGKM0();                                                       \
    MMACL_ALL();                                                               \
    if (!LASTT) PHASE_BAR();                                                   \
  }

  // prologue: stage tile 0 into buf 0 (loop's vmcnt/BAR handles the drain)
  STG(0, 0);

  const int nkt = K >> 6;          // 8 or 32 at our call sites (even)
  for (int kt = 0; kt < nkt - 2; kt += 2) {
    TILE(0, 1, 1, 0, 0, (kt + 1) * 64);
    TILE(1, 1, 1, 0, 0, (kt + 2) * 64);
  }
  TILE(0, 1, 1, 0, 0, (nkt - 1) * 64);   // tile nkt-2: stage last tile
  TILE(1, 0, 0, 1, 1, 0);                // tile nkt-1: drain, compute, no end bar

#undef TILE
#undef MMACL_ALL
#undef READS
#undef STG

  // epilogue: C/D layout col=lane&15, row=(lane>>4)*4+j. 32-bit index math.
#pragma unroll
  for (int mi = 0; mi < 4; ++mi) {
    const int r0 = brow + wm * 64 + mi * 16 + (lane >> 4) * 4;
#pragma unroll
    for (int j = 0; j < 4; ++j) {
      const int rb = (r0 + j) * N;
      const int gcb = bcol + wn * 64 + (lane & 15);
#pragma unroll
      for (int ni = 0; ni < 4; ++ni) {
        const int idx = rb + gcb + ni * 16;
        const float v = acc[mi][ni][j];
        if (EPI == 0) {
          const float hcv = bf2f(((const short*)aux)[idx]);
          const float g = 1.f / (1.f + __expf(-v));
          ((short*)outp)[idx] = f2bf(g * hcv);
        } else if (EPI == 1) {
          ((float*)outp)[idx] = ((const float*)aux)[idx] + v;
        } else if (EPI == 2) {
          const float x3 = v * v * v;
          const float z = 0.7978845608028654f * (v + 0.044715f * x3);
          const float th = 1.f - 2.f / (__expf(2.f * z) + 1.f);   // tanh(z)
          ((short*)outp)[idx] = f2bf(0.5f * v * (1.f + th));
        } else {
          ((float*)outp)[idx] += v;
        }
      }
    }
  }
}

// ---------- launch ----------
extern "C" void kernel_launch(void* const* d_in, const int* in_sizes, int n_in,
                              void* d_out, int out_size, void* d_ws, size_t ws_size,
                              hipStream_t stream) {
  const float* x      = (const float*)d_in[0];
  const float* ln1_w  = (const float*)d_in[1];
  const float* gate_w = (const float*)d_in[2];   // [512][512]
  const float* conv_w = (const float*)d_in[3];   // [512][17]
  const float* proj_w = (const float*)d_in[4];   // [512][512]
  const float* ln2_w  = (const float*)d_in[5];
  const float* mlp_w1 = (const float*)d_in[6];   // [512][2048]
  const float* mlp_w2 = (const float*)d_in[7];   // [2048][512]
  float* out = (float*)d_out;
  char* ws = (char*)d_ws;

  // workspace layout (bytes), all offsets 256B-aligned
  short* hn      = (short*)(ws + 0);                       // 64 MiB  (also hn2 later)
  short* hc      = (short*)(ws + 67108864L);               // 64 MiB  (hc, then u in-place)
  short* mid     = (short*)(ws + 134217728L);              // 256 MiB
  short* gate_wt = (short*)(ws + 402653184L);              // 512 KiB [512][512]
  short* proj_wt = (short*)(ws + 403177472L);              // 512 KiB
  short* w1t     = (short*)(ws + 403701760L);              // 2 MiB   [2048][512]
  short* w2t     = (short*)(ws + 405798912L);              // 2 MiB   [512][2048]
  float* convwT  = (float*)(ws + 407896064L);              // 34 KiB  [17][512]

  const dim3 b256(256);

  // weights -> bf16 transposed (per-call; deterministic, ~5 MB)
  wt_transpose<<<dim3(8, 8),  b256, 0, stream>>>(gate_w, gate_wt, 512, 512);
  wt_transpose<<<dim3(8, 8),  b256, 0, stream>>>(proj_w, proj_wt, 512, 512);
  wt_transpose<<<dim3(8, 32), b256, 0, stream>>>(mlp_w1, w1t, 512, 2048);
  wt_transpose<<<dim3(32, 8), b256, 0, stream>>>(mlp_w2, w2t, 2048, 512);
  convw_transpose<<<34, b256, 0, stream>>>(conv_w, convwT);

  // 1) hn = rmsnorm(x, ln1_w)
  rmsnorm_kernel<<<NTOK / 4, b256, 0, stream>>>(x, ln1_w, hn);
  // 2) hc = causal_dwconv(hn)
  dwconv_kernel<<<NTOK / 4, b256, 0, stream>>>(hn, convwT, hc);
  // 3) u = sigmoid(hn @ gate_w) * hc   (in-place into hc)
  gemm128<0><<<512 * 4, b256, 0, stream>>>(hn, gate_wt, 512, 512, 4, hc, hc);
  // 4) x2 = x + u @ proj_w  -> d_out (f32)
  gemm128<1><<<512 * 4, b256, 0, stream>>>(hc, proj_wt, 512, 512, 4, x, out);
  // 5) hn2 = rmsnorm(x2, ln2_w)  (reuse hn buffer)
  rmsnorm_kernel<<<NTOK / 4, b256, 0, stream>>>(out, ln2_w, hn);
  // 6) mid = gelu(hn2 @ mlp_w1)
  gemm128<2><<<512 * 16, b256, 0, stream>>>(hn, w1t, 512, 2048, 16, nullptr, mid);
  // 7) out += mid @ mlp_w2
  gemm128<3><<<512 * 4, b256, 0, stream>>>(mid, w2t, 2048, 512, 4, nullptr, out);
}